// Round 9
// baseline (92.179 us; speedup 1.0000x reference)
//
#include <hip/hip_runtime.h>

#define LARGEF 1e9f
#define FINF   3.0e38f

constexpr int BLOCK = 256;
constexpr int OPT   = 8;                    // outputs per thread
constexpr int TILE  = BLOCK * OPT;          // 2048 outputs per block
constexpr int CMN   = TILE + 128;           // cmArr logical size (max L = 128)
constexpr int CMP   = CMN + (CMN >> 5) + 4; // padded physical size

// pad every 32 floats by 1 -> breaks the stride-8 bank collision on the
// final cmArr[jl+k+b] reads; float4 writes at 8-aligned logical offsets
// stay within one 32-float segment, so they remain vectorizable.
__device__ __forceinline__ int cpad(int i) { return i + (i >> 5); }

// launch_bounds(256, 8): request 8 waves/EU -> VGPR cap 64 -> 8 blocks/CU.
// Live set in the vh path is ~55 VGPRs after the halo-reuse restructure,
// so this should not spill; it restores the occupancy needed to hide the
// 4x ~900cy HBM loads per wave.
__global__ __launch_bounds__(BLOCK, 8)
void until_kernel(const float* __restrict__ s1, const float* __restrict__ s2,
                  const int* __restrict__ pa, const int* __restrict__ pb,
                  float* __restrict__ out, int T)
{
    const int a = pa[0];
    const int b = pb[0];
    const long base = (long)blockIdx.x * TILE;
    const int tid = (int)threadIdx.x;

    __shared__ float cmArr[CMP];

    const bool vh = (a == 0) && (b == 31 || b == 63 || b == 127);

    if (vh) {
        // ============ all-register van Herk / Gil-Werman path ============
        // L = b+1 divides TILE. Group = L/8 lanes (4/8/16), within one wave.
        // out[j] = max(SUF[j], min(SM[j], CM[j+b])); SUF/SM = within-L-block
        // suffix until/min, CM = within-L-block prefix until.
        const int G    = (b + 1) >> 3;       // lanes per L-block
        const int gm   = G - 1;
        const int lane = tid & 63;
        const int lig  = lane & gm;          // lane index within L-block group

        // ---- main loads: own 8 elements straight to registers ----
        float u[OPT], v[OPT];
        const long jg = base + (long)tid * OPT;
        if (base + TILE <= (long)T) {
            float4 uA = *(const float4*)(s1 + jg);
            float4 uB = *(const float4*)(s1 + jg + 4);
            float4 vA = *(const float4*)(s2 + jg);
            float4 vB = *(const float4*)(s2 + jg + 4);
            u[0]=uA.x;u[1]=uA.y;u[2]=uA.z;u[3]=uA.w;u[4]=uB.x;u[5]=uB.y;u[6]=uB.z;u[7]=uB.w;
            v[0]=vA.x;v[1]=vA.y;v[2]=vA.z;v[3]=vA.w;v[4]=vB.x;v[5]=vB.y;v[6]=vB.z;v[7]=vB.w;
        } else {
            #pragma unroll
            for (int k = 0; k < OPT; ++k) {
                long g = jg + k; if (g > (long)T - 1) g = (long)T - 1;
                u[k] = s1[g]; v[k] = s2[g];
            }
        }

        // ---- thread-local scans (registers); u/v die at the end ----
        float cmR[OPT], smL[OPT], sfL[OPT];
        float p = FINF, r0 = -FINF;
        #pragma unroll
        for (int k = 0; k < OPT; ++k) {
            p  = fminf(p, u[k]);
            r0 = fmaxf(r0, fminf(p, v[k]));
            cmR[k] = r0;                    // local prefix-until
        }
        float smv = FINF, sfv = -FINF;
        #pragma unroll
        for (int k = OPT - 1; k >= 0; --k) {
            sfv = fminf(u[k], fmaxf(v[k], sfv));   // local suffix-until
            smv = fminf(u[k], smv);                // local suffix-min
            smL[k] = smv; sfL[k] = sfv;
        }

        // ---- halo loads (wave 0): issued AFTER local scans so hu/hv can
        //      reuse the dead u/v register budget; latency overlaps the
        //      group-shuffle phase below + co-resident waves ----
        float hu[OPT], hv[OPT];
        const bool haloW = (tid < 64);
        if (haloW) {
            const long hb = base + TILE + (long)lig * OPT;
            if (base + TILE + 128 <= (long)T) {
                float4 A = *(const float4*)(s1 + hb);
                float4 B = *(const float4*)(s1 + hb + 4);
                float4 C = *(const float4*)(s2 + hb);
                float4 D = *(const float4*)(s2 + hb + 4);
                hu[0]=A.x;hu[1]=A.y;hu[2]=A.z;hu[3]=A.w;hu[4]=B.x;hu[5]=B.y;hu[6]=B.z;hu[7]=B.w;
                hv[0]=C.x;hv[1]=C.y;hv[2]=C.z;hv[3]=C.w;hv[4]=D.x;hv[5]=D.y;hv[6]=D.z;hv[7]=D.w;
            } else {
                #pragma unroll
                for (int k = 0; k < OPT; ++k) {
                    long g = hb + k; if (g > (long)T - 1) g = (long)T - 1;
                    hu[k] = s1[g]; hv[k] = s2[g];
                }
            }
        }

        // ---- group (L-block) scans via shuffles, semigroup (P,R) ----
        // combine(A earlier, B later): R = max(R_A, min(P_A, R_B)); P = min
        float Pi = p, Ri = r0;
        for (int d = 1; d < G; d <<= 1) {          // inclusive prefix
            float Pu = __shfl_up(Pi, d);
            float Ru = __shfl_up(Ri, d);
            if (lig >= d) { Ri = fmaxf(Ru, fminf(Pu, Ri)); Pi = fminf(Pu, Pi); }
        }
        float Pp = __shfl_up(Pi, 1), Rp = __shfl_up(Ri, 1);   // exclusive prefix
        if (lig == 0) { Pp = FINF; Rp = -FINF; }

        float Ps = p, Rs = r0;
        for (int d = 1; d < G; d <<= 1) {          // inclusive suffix
            float Pd = __shfl_down(Ps, d);
            float Rd = __shfl_down(Rs, d);
            if (lig + d < G) { Rs = fmaxf(Rs, fminf(Ps, Rd)); Ps = fminf(Ps, Pd); }
        }
        float Ms = __shfl_down(Ps, 1), Re = __shfl_down(Rs, 1); // exclusive suffix
        if (lig == gm) { Ms = FINF; Re = -FINF; }

        // ---- publish full prefix-until CM for own positions ----
        const int jl = tid * OPT;
        {
            float4 cA, cB;
            cA.x = fmaxf(Rp, fminf(Pp, cmR[0]));
            cA.y = fmaxf(Rp, fminf(Pp, cmR[1]));
            cA.z = fmaxf(Rp, fminf(Pp, cmR[2]));
            cA.w = fmaxf(Rp, fminf(Pp, cmR[3]));
            cB.x = fmaxf(Rp, fminf(Pp, cmR[4]));
            cB.y = fmaxf(Rp, fminf(Pp, cmR[5]));
            cB.z = fmaxf(Rp, fminf(Pp, cmR[6]));
            cB.w = fmaxf(Rp, fminf(Pp, cmR[7]));
            const int pj = cpad(jl);        // jl%32 in {0,8,16,24} -> in-segment
            *(float4*)&cmArr[pj]     = cA;
            *(float4*)&cmArr[pj + 4] = cB;
        }

        // ---- halo: wave 0 scans the next L-block from prefetched regs ----
        if (haloW) {
            float hcm[OPT];
            float hp = FINF, hr = -FINF;
            #pragma unroll
            for (int k = 0; k < OPT; ++k) {
                hp = fminf(hp, hu[k]);
                hr = fmaxf(hr, fminf(hp, hv[k]));
                hcm[k] = hr;
            }
            float hPi = hp, hRi = hr;
            for (int d = 1; d < G; d <<= 1) {
                float Pu = __shfl_up(hPi, d);
                float Ru = __shfl_up(hRi, d);
                if (lig >= d) { hRi = fmaxf(Ru, fminf(Pu, hRi)); hPi = fminf(Pu, hPi); }
            }
            float hPp = __shfl_up(hPi, 1), hRp = __shfl_up(hRi, 1);
            if (lig == 0) { hPp = FINF; hRp = -FINF; }
            if (lane < G) {
                float4 cA, cB;
                cA.x = fmaxf(hRp, fminf(hPp, hcm[0]));
                cA.y = fmaxf(hRp, fminf(hPp, hcm[1]));
                cA.z = fmaxf(hRp, fminf(hPp, hcm[2]));
                cA.w = fmaxf(hRp, fminf(hPp, hcm[3]));
                cB.x = fmaxf(hRp, fminf(hPp, hcm[4]));
                cB.y = fmaxf(hRp, fminf(hPp, hcm[5]));
                cB.z = fmaxf(hRp, fminf(hPp, hcm[6]));
                cB.w = fmaxf(hRp, fminf(hPp, hcm[7]));
                const int pj = cpad(TILE + lane * OPT);
                *(float4*)&cmArr[pj]     = cA;
                *(float4*)&cmArr[pj + 4] = cB;
            }
        }
        __syncthreads();

        // ---- final: out[j] = max(SUF, min(SM, CM[j+b])) ----
        float o[OPT];
        #pragma unroll
        for (int k = 0; k < OPT; ++k) {
            const float E   = cmArr[cpad(jl + k + b)];
            const float SUF = fmaxf(sfL[k], fminf(smL[k], Re));
            const float SMv = fminf(smL[k], Ms);
            o[k] = fmaxf(SUF, fminf(SMv, E));
        }
        if (jg + OPT <= (long)T) {
            *(float4*)(out + jg)     = make_float4(o[0], o[1], o[2], o[3]);
            *(float4*)(out + jg + 4) = make_float4(o[4], o[5], o[6], o[7]);
        } else {
            for (int k = 0; k < OPT; ++k)
                if (jg + k < (long)T) out[jg + k] = o[k];
        }
        return;
    }

    // ---- generic fallback (any a, any b): direct global loads ----
    // Correctness net only; the benchmark always takes the vh path.
    {
        const long j0 = base + (long)tid * OPT;
        float m[OPT], o[OPT];
        #pragma unroll
        for (int r = 0; r < OPT; ++r) { m[r] = LARGEF; o[r] = -LARGEF; }
        const long kend = (long)b + OPT - 1;
        for (long k = 0; k <= kend; ++k) {
            long g = j0 + k;
            if (g > (long)T - 1) g = (long)T - 1;
            if (g < 0) g = 0;
            const float v1 = s1[g];
            const float v2 = s2[g];
            #pragma unroll
            for (int r = 0; r < OPT; ++r) {
                const long d = k - r;
                if (d >= 0 && d <= (long)b) {
                    m[r] = fminf(m[r], v1);
                    if (d >= (long)a) o[r] = fmaxf(o[r], fminf(m[r], v2));
                }
            }
        }
        for (int r = 0; r < OPT; ++r)
            if (j0 + r < (long)T) out[j0 + r] = o[r];
    }
}

extern "C" void kernel_launch(void* const* d_in, const int* in_sizes, int n_in,
                              void* d_out, int out_size, void* d_ws, size_t ws_size,
                              hipStream_t stream) {
    const float* s1 = (const float*)d_in[0];
    const float* s2 = (const float*)d_in[1];
    const int*   pa = (const int*)d_in[2];
    const int*   pb = (const int*)d_in[3];
    float* out = (float*)d_out;
    const int T = in_sizes[0];

    const int nblk = (T + TILE - 1) / TILE;
    until_kernel<<<nblk, BLOCK, 0, stream>>>(s1, s2, pa, pb, out, T);
}

// Round 10
// 88.082 us; speedup vs baseline: 1.0465x; 1.0465x over previous
//
#include <hip/hip_runtime.h>

#define LARGEF 1e9f
#define FINF   3.0e38f

constexpr int BLOCK = 256;
constexpr int OPT   = 4;                    // outputs per thread (keeps VGPR <= 64)
constexpr int WTILE = 64 * OPT;             // 256 outputs per wave
constexpr int TILE  = BLOCK * OPT;          // 1024 outputs per block

// Wave-autonomous van Herk: no LDS, no __syncthreads. Each L-block (L=b+1)
// is G = L/OPT consecutive lanes of ONE wave; the cross-block CM term is
// fetched by shuffle from the group G lanes down; the wave's last group
// loads+scans the 128-element halo itself (L1/L2-hit re-reads).
__global__ __launch_bounds__(BLOCK)
void until_kernel(const float* __restrict__ s1, const float* __restrict__ s2,
                  const int* __restrict__ pa, const int* __restrict__ pb,
                  float* __restrict__ out, int T)
{
    const int a = pa[0];
    const int b = pb[0];
    const int tid = (int)threadIdx.x;

    const bool vh = (a == 0) && (b == 31 || b == 63 || b == 127);

    if (vh) {
        const int G    = (b + 1) >> 2;      // lanes per L-block: 8/16/32
        const int gm   = G - 1;
        const int lane = tid & 63;
        const int lig  = lane & gm;         // lane index within L-block group
        const bool lastG = (lane >= 64 - G);

        const long wb  = (long)blockIdx.x * TILE + (long)(tid >> 6) * WTILE;
        const long jg  = wb + (long)lane * OPT;          // own 4 outputs
        const long hbg = wb + WTILE + (long)lig * OPT;   // halo elems (last group)

        // ---- loads (main + halo issued back-to-back, both in flight) ----
        float u[OPT], v[OPT], hu[OPT], hv[OPT];
        const bool fast = (wb + WTILE + 128 <= (long)T);
        if (fast) {
            float4 U = *(const float4*)(s1 + jg);
            float4 V = *(const float4*)(s2 + jg);
            u[0]=U.x; u[1]=U.y; u[2]=U.z; u[3]=U.w;
            v[0]=V.x; v[1]=V.y; v[2]=V.z; v[3]=V.w;
            if (lastG) {
                float4 HU = *(const float4*)(s1 + hbg);
                float4 HV = *(const float4*)(s2 + hbg);
                hu[0]=HU.x; hu[1]=HU.y; hu[2]=HU.z; hu[3]=HU.w;
                hv[0]=HV.x; hv[1]=HV.y; hv[2]=HV.z; hv[3]=HV.w;
            }
        } else {
            #pragma unroll
            for (int k = 0; k < OPT; ++k) {
                long g = jg + k; if (g > (long)T - 1) g = (long)T - 1;
                u[k] = s1[g]; v[k] = s2[g];
            }
            if (lastG) {
                #pragma unroll
                for (int k = 0; k < OPT; ++k) {
                    long g = hbg + k; if (g > (long)T - 1) g = (long)T - 1;
                    hu[k] = s1[g]; hv[k] = s2[g];
                }
            }
        }

        // ---- thread-local scans ----
        float cmF[OPT], smL[OPT], sfL[OPT];
        float p = FINF, r0 = -FINF;
        #pragma unroll
        for (int k = 0; k < OPT; ++k) {
            p  = fminf(p, u[k]);
            r0 = fmaxf(r0, fminf(p, v[k]));
            cmF[k] = r0;                    // local prefix-until (composed below)
        }
        float smv = FINF, sfv = -FINF;
        #pragma unroll
        for (int k = OPT - 1; k >= 0; --k) {
            sfv = fminf(u[k], fmaxf(v[k], sfv));   // local suffix-until
            smv = fminf(u[k], smv);                // local suffix-min
            smL[k] = smv; sfL[k] = sfv;
        }

        // ---- group scans via shuffles; semigroup (P,R):
        //      combine(A earlier, B later): R = max(R_A, min(P_A, R_B)); P = min
        float Pi = p, Ri = r0;
        for (int d = 1; d < G; d <<= 1) {          // inclusive prefix
            float Pu = __shfl_up(Pi, d);
            float Ru = __shfl_up(Ri, d);
            if (lig >= d) { Ri = fmaxf(Ru, fminf(Pu, Ri)); Pi = fminf(Pu, Pi); }
        }
        float Pp = __shfl_up(Pi, 1), Rp = __shfl_up(Ri, 1);   // exclusive prefix
        if (lig == 0) { Pp = FINF; Rp = -FINF; }

        float Ps = p, Rs = r0;
        for (int d = 1; d < G; d <<= 1) {          // inclusive suffix
            float Pd = __shfl_down(Ps, d);
            float Rd = __shfl_down(Rs, d);
            if (lig + d < G) { Rs = fmaxf(Rs, fminf(Ps, Rd)); Ps = fminf(Ps, Pd); }
        }
        float Ms = __shfl_down(Ps, 1), Re = __shfl_down(Rs, 1); // exclusive suffix
        if (lig == gm) { Ms = FINF; Re = -FINF; }

        // ---- compose full within-block prefix-until for own positions ----
        #pragma unroll
        for (int k = 0; k < OPT; ++k)
            cmF[k] = fmaxf(Rp, fminf(Pp, cmF[k]));

        // ---- next-block CM: shuffle from the group G lanes down ----
        float cmN[OPT];
        #pragma unroll
        for (int k = 0; k < OPT; ++k) cmN[k] = __shfl_down(cmF[k], G);
        float prevN = __shfl_down(cmF[OPT - 1], G - 1);   // offset t-1 donor

        // ---- last group: scan own halo block instead ----
        if (lastG) {
            float hcmF[OPT];
            float hp = FINF, hr = -FINF;
            #pragma unroll
            for (int k = 0; k < OPT; ++k) {
                hp = fminf(hp, hu[k]);
                hr = fmaxf(hr, fminf(hp, hv[k]));
                hcmF[k] = hr;
            }
            float hPi = hp, hRi = hr;
            for (int d = 1; d < G; d <<= 1) {
                float Pu = __shfl_up(hPi, d);
                float Ru = __shfl_up(hRi, d);
                if (lig >= d) { hRi = fmaxf(Ru, fminf(Pu, hRi)); hPi = fminf(Pu, hPi); }
            }
            float hPp = __shfl_up(hPi, 1), hRp = __shfl_up(hRi, 1);
            if (lig == 0) { hPp = FINF; hRp = -FINF; }
            #pragma unroll
            for (int k = 0; k < OPT; ++k)
                hcmF[k] = fmaxf(hRp, fminf(hPp, hcmF[k]));
            prevN = __shfl_up(hcmF[OPT - 1], 1);
            #pragma unroll
            for (int k = 0; k < OPT; ++k) cmN[k] = hcmF[k];
        }

        // ---- final: out[j] = max(SUF, min(SM, CM_next[t+k-1])) ----
        float o[OPT];
        {
            const float E   = (lig == 0) ? -FINF : prevN;  // t=0: out = SUF
            const float SUF = fmaxf(sfL[0], fminf(smL[0], Re));
            const float SM  = fminf(smL[0], Ms);
            o[0] = fmaxf(SUF, fminf(SM, E));
        }
        #pragma unroll
        for (int k = 1; k < OPT; ++k) {
            const float E   = cmN[k - 1];
            const float SUF = fmaxf(sfL[k], fminf(smL[k], Re));
            const float SM  = fminf(smL[k], Ms);
            o[k] = fmaxf(SUF, fminf(SM, E));
        }

        if (jg + OPT <= (long)T) {
            *(float4*)(out + jg) = make_float4(o[0], o[1], o[2], o[3]);
        } else {
            for (int k = 0; k < OPT; ++k)
                if (jg + k < (long)T) out[jg + k] = o[k];
        }
        return;
    }

    // ---- generic fallback (any a, any b): direct global loads ----
    // Correctness net only; the benchmark always takes the vh path.
    {
        const long j0 = (long)blockIdx.x * TILE + (long)tid * OPT;
        float m[OPT], o[OPT];
        #pragma unroll
        for (int r = 0; r < OPT; ++r) { m[r] = LARGEF; o[r] = -LARGEF; }
        const long kend = (long)b + OPT - 1;
        for (long k = 0; k <= kend; ++k) {
            long g = j0 + k;
            if (g > (long)T - 1) g = (long)T - 1;
            if (g < 0) g = 0;
            const float v1 = s1[g];
            const float v2 = s2[g];
            #pragma unroll
            for (int r = 0; r < OPT; ++r) {
                const long d = k - r;
                if (d >= 0 && d <= (long)b) {
                    m[r] = fminf(m[r], v1);
                    if (d >= (long)a) o[r] = fmaxf(o[r], fminf(m[r], v2));
                }
            }
        }
        for (int r = 0; r < OPT; ++r)
            if (j0 + r < (long)T) out[j0 + r] = o[r];
    }
}

extern "C" void kernel_launch(void* const* d_in, const int* in_sizes, int n_in,
                              void* d_out, int out_size, void* d_ws, size_t ws_size,
                              hipStream_t stream) {
    const float* s1 = (const float*)d_in[0];
    const float* s2 = (const float*)d_in[1];
    const int*   pa = (const int*)d_in[2];
    const int*   pb = (const int*)d_in[3];
    float* out = (float*)d_out;
    const int T = in_sizes[0];

    const int nblk = (T + TILE - 1) / TILE;
    until_kernel<<<nblk, BLOCK, 0, stream>>>(s1, s2, pa, pb, out, T);
}

// Round 11
// 85.042 us; speedup vs baseline: 1.0839x; 1.0357x over previous
//
#include <hip/hip_runtime.h>

#define LARGEF 1e9f
#define FINF   3.0e38f

constexpr int BLOCK = 256;
constexpr int OPT   = 8;                    // outputs per thread
constexpr int WTILE = 64 * OPT;             // 512 outputs per wave
constexpr int TILE  = BLOCK * OPT;          // 2048 outputs per block

// Wave-autonomous van Herk: no LDS, no __syncthreads. Each L-block (L=b+1)
// is G = L/OPT consecutive lanes of ONE wave; the cross-block CM term is
// fetched by shuffle from the group G lanes down; the wave's last group
// loads+scans the L-element halo itself (L1/L2-hit re-reads, 25% extra).
// Halo loads are issued AFTER the local scans so hu/hv reuse the dead u/v
// register budget (no launch_bounds cap -- R9 showed capping below the
// live set causes scratch spills and a 7x slowdown).
__global__ __launch_bounds__(BLOCK)
void until_kernel(const float* __restrict__ s1, const float* __restrict__ s2,
                  const int* __restrict__ pa, const int* __restrict__ pb,
                  float* __restrict__ out, int T)
{
    const int a = pa[0];
    const int b = pb[0];
    const int tid = (int)threadIdx.x;

    const bool vh = (a == 0) && (b == 31 || b == 63 || b == 127);

    if (vh) {
        const int G    = (b + 1) >> 3;      // lanes per L-block: 4/8/16
        const int gm   = G - 1;
        const int lane = tid & 63;
        const int lig  = lane & gm;         // lane index within L-block group
        const bool lastG = (lane >= 64 - G);

        const long wb  = (long)blockIdx.x * TILE + (long)(tid >> 6) * WTILE;
        const long jg  = wb + (long)lane * OPT;          // own 8 outputs
        const long hbg = wb + WTILE + (long)lig * OPT;   // halo elems (last group)
        const bool fast = (wb + WTILE + 128 <= (long)T);

        // ---- main loads: own 8 elements straight to registers ----
        float u[OPT], v[OPT];
        if (fast) {
            float4 uA = *(const float4*)(s1 + jg);
            float4 uB = *(const float4*)(s1 + jg + 4);
            float4 vA = *(const float4*)(s2 + jg);
            float4 vB = *(const float4*)(s2 + jg + 4);
            u[0]=uA.x;u[1]=uA.y;u[2]=uA.z;u[3]=uA.w;u[4]=uB.x;u[5]=uB.y;u[6]=uB.z;u[7]=uB.w;
            v[0]=vA.x;v[1]=vA.y;v[2]=vA.z;v[3]=vA.w;v[4]=vB.x;v[5]=vB.y;v[6]=vB.z;v[7]=vB.w;
        } else {
            #pragma unroll
            for (int k = 0; k < OPT; ++k) {
                long g = jg + k; if (g > (long)T - 1) g = (long)T - 1;
                u[k] = s1[g]; v[k] = s2[g];
            }
        }

        // ---- thread-local scans (u/v die at the end) ----
        float cmF[OPT], smL[OPT], sfL[OPT];
        float p = FINF, r0 = -FINF;
        #pragma unroll
        for (int k = 0; k < OPT; ++k) {
            p  = fminf(p, u[k]);
            r0 = fmaxf(r0, fminf(p, v[k]));
            cmF[k] = r0;                    // local prefix-until (composed below)
        }
        float smv = FINF, sfv = -FINF;
        #pragma unroll
        for (int k = OPT - 1; k >= 0; --k) {
            sfv = fminf(u[k], fmaxf(v[k], sfv));   // local suffix-until
            smv = fminf(u[k], smv);                // local suffix-min
            smL[k] = smv; sfL[k] = sfv;
        }

        // ---- halo loads (last group only), after scans: reuse dead u/v ----
        float hu[OPT], hv[OPT];
        if (lastG) {
            if (fast) {
                float4 A = *(const float4*)(s1 + hbg);
                float4 B = *(const float4*)(s1 + hbg + 4);
                float4 C = *(const float4*)(s2 + hbg);
                float4 D = *(const float4*)(s2 + hbg + 4);
                hu[0]=A.x;hu[1]=A.y;hu[2]=A.z;hu[3]=A.w;hu[4]=B.x;hu[5]=B.y;hu[6]=B.z;hu[7]=B.w;
                hv[0]=C.x;hv[1]=C.y;hv[2]=C.z;hv[3]=C.w;hv[4]=D.x;hv[5]=D.y;hv[6]=D.z;hv[7]=D.w;
            } else {
                #pragma unroll
                for (int k = 0; k < OPT; ++k) {
                    long g = hbg + k; if (g > (long)T - 1) g = (long)T - 1;
                    hu[k] = s1[g]; hv[k] = s2[g];
                }
            }
        }

        // ---- group scans via shuffles; semigroup (P,R):
        //      combine(A earlier, B later): R = max(R_A, min(P_A, R_B)); P = min
        float Pi = p, Ri = r0;
        for (int d = 1; d < G; d <<= 1) {          // inclusive prefix
            float Pu = __shfl_up(Pi, d);
            float Ru = __shfl_up(Ri, d);
            if (lig >= d) { Ri = fmaxf(Ru, fminf(Pu, Ri)); Pi = fminf(Pu, Pi); }
        }
        float Pp = __shfl_up(Pi, 1), Rp = __shfl_up(Ri, 1);   // exclusive prefix
        if (lig == 0) { Pp = FINF; Rp = -FINF; }

        float Ps = p, Rs = r0;
        for (int d = 1; d < G; d <<= 1) {          // inclusive suffix
            float Pd = __shfl_down(Ps, d);
            float Rd = __shfl_down(Rs, d);
            if (lig + d < G) { Rs = fmaxf(Rs, fminf(Ps, Rd)); Ps = fminf(Ps, Pd); }
        }
        float Ms = __shfl_down(Ps, 1), Re = __shfl_down(Rs, 1); // exclusive suffix
        if (lig == gm) { Ms = FINF; Re = -FINF; }

        // ---- compose full within-block prefix-until for own positions ----
        #pragma unroll
        for (int k = 0; k < OPT; ++k)
            cmF[k] = fmaxf(Rp, fminf(Pp, cmF[k]));

        // ---- next-block CM: shuffle from the group G lanes down ----
        float cmN[OPT];
        #pragma unroll
        for (int k = 0; k < OPT; ++k) cmN[k] = __shfl_down(cmF[k], G);
        float prevN = __shfl_down(cmF[OPT - 1], G - 1);   // donor of pos-1 term

        // ---- last group: scan own halo block instead ----
        if (lastG) {
            float hcmF[OPT];
            float hp = FINF, hr = -FINF;
            #pragma unroll
            for (int k = 0; k < OPT; ++k) {
                hp = fminf(hp, hu[k]);
                hr = fmaxf(hr, fminf(hp, hv[k]));
                hcmF[k] = hr;
            }
            float hPi = hp, hRi = hr;
            for (int d = 1; d < G; d <<= 1) {
                float Pu = __shfl_up(hPi, d);
                float Ru = __shfl_up(hRi, d);
                if (lig >= d) { hRi = fmaxf(Ru, fminf(Pu, hRi)); hPi = fminf(Pu, hPi); }
            }
            float hPp = __shfl_up(hPi, 1), hRp = __shfl_up(hRi, 1);
            if (lig == 0) { hPp = FINF; hRp = -FINF; }
            #pragma unroll
            for (int k = 0; k < OPT; ++k)
                hcmF[k] = fmaxf(hRp, fminf(hPp, hcmF[k]));
            prevN = __shfl_up(hcmF[OPT - 1], 1);
            #pragma unroll
            for (int k = 0; k < OPT; ++k) cmN[k] = hcmF[k];
        }

        // ---- final: out[j] = max(SUF, min(SM, CM_next[pos-1])) ----
        float o[OPT];
        {
            const float E   = (lig == 0) ? -FINF : prevN;  // pos=0: out = SUF
            const float SUF = fmaxf(sfL[0], fminf(smL[0], Re));
            const float SM  = fminf(smL[0], Ms);
            o[0] = fmaxf(SUF, fminf(SM, E));
        }
        #pragma unroll
        for (int k = 1; k < OPT; ++k) {
            const float E   = cmN[k - 1];
            const float SUF = fmaxf(sfL[k], fminf(smL[k], Re));
            const float SM  = fminf(smL[k], Ms);
            o[k] = fmaxf(SUF, fminf(SM, E));
        }

        if (jg + OPT <= (long)T) {
            *(float4*)(out + jg)     = make_float4(o[0], o[1], o[2], o[3]);
            *(float4*)(out + jg + 4) = make_float4(o[4], o[5], o[6], o[7]);
        } else {
            for (int k = 0; k < OPT; ++k)
                if (jg + k < (long)T) out[jg + k] = o[k];
        }
        return;
    }

    // ---- generic fallback (any a, any b): direct global loads ----
    // Correctness net only; the benchmark always takes the vh path.
    {
        const long j0 = (long)blockIdx.x * TILE + (long)tid * OPT;
        float m[OPT], o[OPT];
        #pragma unroll
        for (int r = 0; r < OPT; ++r) { m[r] = LARGEF; o[r] = -LARGEF; }
        const long kend = (long)b + OPT - 1;
        for (long k = 0; k <= kend; ++k) {
            long g = j0 + k;
            if (g > (long)T - 1) g = (long)T - 1;
            if (g < 0) g = 0;
            const float v1 = s1[g];
            const float v2 = s2[g];
            #pragma unroll
            for (int r = 0; r < OPT; ++r) {
                const long d = k - r;
                if (d >= 0 && d <= (long)b) {
                    m[r] = fminf(m[r], v1);
                    if (d >= (long)a) o[r] = fmaxf(o[r], fminf(m[r], v2));
                }
            }
        }
        for (int r = 0; r < OPT; ++r)
            if (j0 + r < (long)T) out[j0 + r] = o[r];
    }
}

extern "C" void kernel_launch(void* const* d_in, const int* in_sizes, int n_in,
                              void* d_out, int out_size, void* d_ws, size_t ws_size,
                              hipStream_t stream) {
    const float* s1 = (const float*)d_in[0];
    const float* s2 = (const float*)d_in[1];
    const int*   pa = (const int*)d_in[2];
    const int*   pb = (const int*)d_in[3];
    float* out = (float*)d_out;
    const int T = in_sizes[0];

    const int nblk = (T + TILE - 1) / TILE;
    until_kernel<<<nblk, BLOCK, 0, stream>>>(s1, s2, pa, pb, out, T);
}